// Round 1
// baseline (2882.271 us; speedup 1.0000x reference)
//
#include <hip/hip_runtime.h>
#include <math.h>

#define B_ 2048
#define M_ 64
#define H_ 256
#define E_ 256
#define U_ 1000
#define V_ 50000

// ---- d_out layout (return order: output, hidden_new, emb, gru_output, attn_weights) ----
static const long long OUT_HID_OFF  = (long long)B_ * V_;               // 102,400,000
static const long long OUT_EMB_OFF  = OUT_HID_OFF + (long long)B_ * H_;
static const long long OUT_GRU_OFF  = OUT_EMB_OFF + (long long)B_ * H_;
static const long long OUT_ATTN_OFF = OUT_GRU_OFF + (long long)B_ * H_;
// scratch stash inside the big "output" region (overwritten by out_gemm at the end)
static const long long ST_CTX  = 0;                       // B*H floats
static const long long ST_WIHT = (long long)B_ * H_;      // 512*768 floats
static const long long ST_WHHT = ST_WIHT + 512 * 768;     // 256*768 floats

// ---------------------------------------------------------------------------
// Tiled transpose: dst[cols][rows] = src[rows][cols]^T
// ---------------------------------------------------------------------------
__global__ __launch_bounds__(256) void transpose_kernel(
    const float* __restrict__ src, float* __restrict__ dst, int rows, int cols)
{
    __shared__ float tile[32][33];
    const int bx = blockIdx.x * 32;   // col base (src)
    const int by = blockIdx.y * 32;   // row base (src)
    const int tx = threadIdx.x;       // 0..31
    const int ty = threadIdx.y;       // 0..7
    #pragma unroll
    for (int i = 0; i < 32; i += 8) {
        int r = by + ty + i, c = bx + tx;
        tile[ty + i][tx] = (r < rows && c < cols) ? src[r * cols + c] : 0.f;
    }
    __syncthreads();
    #pragma unroll
    for (int i = 0; i < 32; i += 8) {
        int r = bx + ty + i, c = by + tx;   // dst coords (r = src col, c = src row)
        if (r < cols && c < rows) dst[r * rows + c] = tile[tx][ty + i];
    }
}

// ---------------------------------------------------------------------------
// Attention kernel: one block per batch element, 256 threads.
//   Computes attn_weights (output) and context (stash).
//   Thread (tm,tk): m-rows tm*8..tm*8+7, k-cols {tk + 32*kk}.
//   smem (64 KiB) phase-overlaid: [h_s|hta_s] -> io tile -> ioa tile -> [e_s|attn_s]
// ---------------------------------------------------------------------------
__global__ __launch_bounds__(256) void attn_kernel(
    const float* __restrict__ hidden,        // (1,B,H)
    const float* __restrict__ inter_output,  // (B,M,H)
    const float* __restrict__ W_inter,       // (U,H,H)
    const float* __restrict__ b_inter,       // (U,H)
    const float* __restrict__ W_hidden,      // (U,H,H)
    const float* __restrict__ b_hidden,      // (U,H)
    const float* __restrict__ W_scale,       // (U,H,1)
    const float* __restrict__ W_lt1,         // (U,2H,H)
    const float* __restrict__ b_lt1,         // (U,H)
    const int*   __restrict__ user_list,     // (B,)
    float* __restrict__ ctx_out,             // (B,H) stash
    float* __restrict__ attn_out)            // (B,M) output
{
    __shared__ float smem[64 * 256];         // 64 KiB exactly
    float* h_s    = smem;                    // [256]  phase A
    float* hta_s  = smem + 256;              // [256]  phase A
    float* io_s   = smem;                    // [64][256] phase B (io, then ioa)
    float* e_s    = smem;                    // [64]   phase C
    float* attn_s = smem + 64;               // [64]   phase C

    const int b   = blockIdx.x;
    const int tid = threadIdx.x;
    const int tm  = tid >> 5;     // 0..7
    const int tk  = tid & 31;     // 0..31

    const int u = user_list[b];
    const float* __restrict__ Wh  = W_hidden + (size_t)u * (H_ * H_);
    const float* __restrict__ Wi  = W_inter  + (size_t)u * (H_ * H_);
    const float* __restrict__ Wl  = W_lt1    + (size_t)u * (2 * H_ * H_);
    const float* __restrict__ iob = inter_output + (size_t)b * (M_ * H_);

    // ---------------- phase A: ht_a, then per-thread base[k-set] in registers
    h_s[tid] = hidden[b * H_ + tid];
    __syncthreads();
    {
        float acc = b_hidden[u * H_ + tid];
        #pragma unroll 4
        for (int h = 0; h < H_; ++h) acc += h_s[h] * Wh[h * H_ + tid];
        hta_s[tid] = acc;
    }
    __syncthreads();
    float base[8];
    #pragma unroll
    for (int kk = 0; kk < 8; ++kk) base[kk] = b_lt1[u * H_ + tk + 32 * kk];
    for (int j = 0; j < H_; ++j) {
        float hv = hta_s[j];
        const float* wr = &Wl[j * H_ + tk];   // top half rows (j < H)
        #pragma unroll
        for (int kk = 0; kk < 8; ++kk) base[kk] += hv * wr[32 * kk];
    }
    __syncthreads();   // h_s/hta_s dead; smem becomes io tile

    // ---------------- phase B: stage io tile (flat copy, coalesced, conflict-free)
    {
        const float4* src = (const float4*)iob;
        float4* dst = (float4*)io_s;
        #pragma unroll
        for (int q = 0; q < 16; ++q) dst[q * 256 + tid] = src[q * 256 + tid];
    }
    __syncthreads();

    // ---------------- GEMM1: io_a = io @ W_inter  (acc[mm][kk])
    float acc[8][8];
    #pragma unroll
    for (int mm = 0; mm < 8; ++mm)
        #pragma unroll
        for (int kk = 0; kk < 8; ++kk) acc[mm][kk] = 0.f;

    #pragma unroll 2
    for (int h4 = 0; h4 < H_; h4 += 4) {
        float4 av[8];
        #pragma unroll
        for (int mm = 0; mm < 8; ++mm)
            av[mm] = *(const float4*)&io_s[(tm * 8 + mm) * H_ + h4];
        #pragma unroll
        for (int hh = 0; hh < 4; ++hh) {
            const float* wr = &Wi[(h4 + hh) * H_ + tk];
            float w[8];
            #pragma unroll
            for (int kk = 0; kk < 8; ++kk) w[kk] = wr[32 * kk];
            #pragma unroll
            for (int mm = 0; mm < 8; ++mm) {
                float a = ((const float*)&av[mm])[hh];
                #pragma unroll
                for (int kk = 0; kk < 8; ++kk) acc[mm][kk] += a * w[kk];
            }
        }
    }
    __syncthreads();   // all GEMM1 reads of io_s complete
    // write ioa = acc + b_inter back into io_s (2-way bank = free)
    #pragma unroll
    for (int kk = 0; kk < 8; ++kk) {
        float bi = b_inter[u * H_ + tk + 32 * kk];
        #pragma unroll
        for (int mm = 0; mm < 8; ++mm)
            io_s[(tm * 8 + mm) * H_ + tk + 32 * kk] = acc[mm][kk] + bi;
    }
    __syncthreads();

    // ---------------- GEMM2: z = ioa @ W_lt1[H:2H] + base; res = tanh(z)
    #pragma unroll
    for (int mm = 0; mm < 8; ++mm)
        #pragma unroll
        for (int kk = 0; kk < 8; ++kk) acc[mm][kk] = 0.f;
    const float* __restrict__ Wlb = Wl + H_ * H_;   // rows 256..511
    #pragma unroll 2
    for (int j4 = 0; j4 < H_; j4 += 4) {
        float4 av[8];
        #pragma unroll
        for (int mm = 0; mm < 8; ++mm)
            av[mm] = *(const float4*)&io_s[(tm * 8 + mm) * H_ + j4];
        #pragma unroll
        for (int jj = 0; jj < 4; ++jj) {
            const float* wr = &Wlb[(j4 + jj) * H_ + tk];
            float w[8];
            #pragma unroll
            for (int kk = 0; kk < 8; ++kk) w[kk] = wr[32 * kk];
            #pragma unroll
            for (int mm = 0; mm < 8; ++mm) {
                float a = ((const float*)&av[mm])[jj];
                #pragma unroll
                for (int kk = 0; kk < 8; ++kk) acc[mm][kk] += a * w[kk];
            }
        }
    }
    // energies partial per thread; wsc from global (8 scalars)
    float wsc[8];
    #pragma unroll
    for (int kk = 0; kk < 8; ++kk) wsc[kk] = W_scale[u * H_ + tk + 32 * kk];
    float pe[8];
    #pragma unroll
    for (int mm = 0; mm < 8; ++mm) {
        float s = 0.f;
        #pragma unroll
        for (int kk = 0; kk < 8; ++kk) {
            float r = tanhf(acc[mm][kk] + base[kk]);
            s += r * wsc[kk];
        }
        pe[mm] = s;
    }
    __syncthreads();   // io_s dead; smem becomes e_s/attn_s
    // reduce over tk (contiguous 32-lane half-wave)
    #pragma unroll
    for (int mm = 0; mm < 8; ++mm) {
        float s = pe[mm];
        #pragma unroll
        for (int off = 16; off > 0; off >>= 1) s += __shfl_xor(s, off, 32);
        if (tk == 0) e_s[tm * 8 + mm] = s;
    }
    __syncthreads();
    // softmax over M=64 (wave 0); b_scale cancels in softmax
    if (tid < 64) {
        float e = e_s[tid];
        float mx = e;
        #pragma unroll
        for (int off = 32; off > 0; off >>= 1) mx = fmaxf(mx, __shfl_xor(mx, off, 64));
        float p = expf(e - mx);
        float sm = p;
        #pragma unroll
        for (int off = 32; off > 0; off >>= 1) sm += __shfl_xor(sm, off, 64);
        float aw = p / sm;
        attn_s[tid] = aw;
        attn_out[b * M_ + tid] = aw;
    }
    __syncthreads();
    // context[h] = sum_m attn[m] * io[m][h]  (io re-read from global; L2-hot)
    {
        float ctx = 0.f;
        #pragma unroll 4
        for (int m = 0; m < M_; ++m) ctx += attn_s[m] * iob[m * H_ + tid];
        ctx_out[b * H_ + tid] = ctx;
    }
}

// ---------------------------------------------------------------------------
// GRU kernel: 8 batches per block, 256 threads (thread = gate column j, j+256, j+512).
// Also writes through emb to d_out. Uses pre-transposed W_ihT (512x768), W_hhT (256x768).
// ---------------------------------------------------------------------------
__global__ __launch_bounds__(256) void gru_kernel(
    const float* __restrict__ emb,     // (B,1,E)
    const float* __restrict__ hidden,  // (1,B,H)
    const float* __restrict__ ctx,     // (B,H)
    const float* __restrict__ WihT,    // (512,768)
    const float* __restrict__ WhhT,    // (256,768)
    const float* __restrict__ b_ih,    // (768,)
    const float* __restrict__ b_hh,    // (768,)
    float* __restrict__ hid_out,       // (B,H)
    float* __restrict__ gru_out,       // (B,H)
    float* __restrict__ emb_out)       // (B,E)
{
    __shared__ float xT[512 * 8];   // [k][bb] 16 KiB
    __shared__ float hT[256 * 8];   // [k][bb]  8 KiB
    const int tid = threadIdx.x;
    const int b0  = blockIdx.x * 8;
    const int bb  = tid >> 5;       // 0..7
    const int kf  = tid & 31;       // float4 index
    #pragma unroll
    for (int p = 0; p < 2; ++p) {
        int k4 = kf + 32 * p;       // 0..63
        float4 fe = ((const float4*)(emb + (size_t)(b0 + bb) * E_))[k4];
        ((float4*)(emb_out + (size_t)(b0 + bb) * E_))[k4] = fe;   // emb passthrough
        xT[(4 * k4 + 0) * 8 + bb] = fe.x; xT[(4 * k4 + 1) * 8 + bb] = fe.y;
        xT[(4 * k4 + 2) * 8 + bb] = fe.z; xT[(4 * k4 + 3) * 8 + bb] = fe.w;
        float4 fc = ((const float4*)(ctx + (size_t)(b0 + bb) * H_))[k4];
        xT[(E_ + 4 * k4 + 0) * 8 + bb] = fc.x; xT[(E_ + 4 * k4 + 1) * 8 + bb] = fc.y;
        xT[(E_ + 4 * k4 + 2) * 8 + bb] = fc.z; xT[(E_ + 4 * k4 + 3) * 8 + bb] = fc.w;
        float4 fh = ((const float4*)(hidden + (size_t)(b0 + bb) * H_))[k4];
        hT[(4 * k4 + 0) * 8 + bb] = fh.x; hT[(4 * k4 + 1) * 8 + bb] = fh.y;
        hT[(4 * k4 + 2) * 8 + bb] = fh.z; hT[(4 * k4 + 3) * 8 + bb] = fh.w;
    }
    __syncthreads();
    float ar[8], az[8], ani[8], anh[8];
    #pragma unroll
    for (int i = 0; i < 8; ++i) { ar[i] = 0.f; az[i] = 0.f; ani[i] = 0.f; anh[i] = 0.f; }
    #pragma unroll 2
    for (int k = 0; k < 512; ++k) {
        float wr = WihT[k * 768 + tid];
        float wz = WihT[k * 768 + 256 + tid];
        float wn = WihT[k * 768 + 512 + tid];
        float4 x0 = *(const float4*)&xT[k * 8];
        float4 x1 = *(const float4*)&xT[k * 8 + 4];
        float xa[8] = {x0.x, x0.y, x0.z, x0.w, x1.x, x1.y, x1.z, x1.w};
        #pragma unroll
        for (int i = 0; i < 8; ++i) {
            ar[i]  += wr * xa[i];
            az[i]  += wz * xa[i];
            ani[i] += wn * xa[i];
        }
    }
    #pragma unroll 2
    for (int k = 0; k < 256; ++k) {
        float wr = WhhT[k * 768 + tid];
        float wz = WhhT[k * 768 + 256 + tid];
        float wn = WhhT[k * 768 + 512 + tid];
        float4 h0 = *(const float4*)&hT[k * 8];
        float4 h1 = *(const float4*)&hT[k * 8 + 4];
        float ha[8] = {h0.x, h0.y, h0.z, h0.w, h1.x, h1.y, h1.z, h1.w};
        #pragma unroll
        for (int i = 0; i < 8; ++i) {
            ar[i]  += wr * ha[i];
            az[i]  += wz * ha[i];
            anh[i] += wn * ha[i];
        }
    }
    const float bir = b_ih[tid] + b_hh[tid];
    const float biz = b_ih[H_ + tid] + b_hh[H_ + tid];
    const float bin = b_ih[2 * H_ + tid];
    const float bhn = b_hh[2 * H_ + tid];
    #pragma unroll
    for (int i = 0; i < 8; ++i) {
        float r  = 1.f / (1.f + expf(-(ar[i] + bir)));
        float z  = 1.f / (1.f + expf(-(az[i] + biz)));
        float n  = tanhf(ani[i] + bin + r * (anh[i] + bhn));
        float h0 = hT[tid * 8 + i];
        float hn = (1.f - z) * n + z * h0;
        hid_out[(size_t)(b0 + i) * H_ + tid] = hn;
        gru_out[(size_t)(b0 + i) * H_ + tid] = hn;
    }
}

// ---------------------------------------------------------------------------
// Output GEMM: out[b][v] = hnew[b][:] . W_out[v][:] + b_out[v]
// Block tile 128b x 256v; thread tile 16b x 8v. W via LDS, hnew via broadcast loads.
// ---------------------------------------------------------------------------
__global__ __launch_bounds__(256) void out_gemm(
    const float* __restrict__ A,     // hnew (B,H)
    const float* __restrict__ W,     // (V,H)
    const float* __restrict__ bias,  // (V,)
    float* __restrict__ out)         // (B,V)
{
    __shared__ float W_s[16][260];
    const int tid = threadIdx.x;
    const int tb  = tid >> 5;        // 0..7  -> 16 b-rows each
    const int tv  = tid & 31;        // 0..31 -> 8 v-cols each
    const int v0  = blockIdx.x * 256;
    const int b0  = blockIdx.y * 128;
    float acc[16][8];
    #pragma unroll
    for (int i = 0; i < 16; ++i)
        #pragma unroll
        for (int j = 0; j < 8; ++j) acc[i][j] = 0.f;

    for (int h0 = 0; h0 < H_; h0 += 16) {
        // stage W chunk: 256 v-rows x 16 h (transposed into W_s[h][v])
        #pragma unroll
        for (int i = 0; i < 4; ++i) {
            int idx = i * 256 + tid;     // 0..1023
            int vl  = idx >> 2;          // 0..255
            int c   = idx & 3;           // f4 chunk within 16 h
            int v   = v0 + vl;
            float4 f = make_float4(0.f, 0.f, 0.f, 0.f);
            if (v < V_) f = ((const float4*)(W + (size_t)v * H_ + h0))[c];
            W_s[4 * c + 0][vl] = f.x; W_s[4 * c + 1][vl] = f.y;
            W_s[4 * c + 2][vl] = f.z; W_s[4 * c + 3][vl] = f.w;
        }
        __syncthreads();
        #pragma unroll 4
        for (int hh = 0; hh < 16; ++hh) {
            float w[8];
            float4 w0 = *(const float4*)&W_s[hh][tv * 8];
            float4 w1 = *(const float4*)&W_s[hh][tv * 8 + 4];
            w[0] = w0.x; w[1] = w0.y; w[2] = w0.z; w[3] = w0.w;
            w[4] = w1.x; w[5] = w1.y; w[6] = w1.z; w[7] = w1.w;
            const float* ap = A + (size_t)(b0 + tb * 16) * H_ + (h0 + hh);
            #pragma unroll
            for (int i = 0; i < 16; ++i) {
                float a = ap[i * H_];    // broadcast load (L1/L2-hot)
                #pragma unroll
                for (int j = 0; j < 8; ++j) acc[i][j] += a * w[j];
            }
        }
        __syncthreads();
    }
    const int v = v0 + tv * 8;
    if (v < V_) {
        float4 bo0 = *(const float4*)(bias + v);
        float4 bo1 = *(const float4*)(bias + v + 4);
        #pragma unroll
        for (int i = 0; i < 16; ++i) {
            float4 o0, o1;
            o0.x = acc[i][0] + bo0.x; o0.y = acc[i][1] + bo0.y;
            o0.z = acc[i][2] + bo0.z; o0.w = acc[i][3] + bo0.w;
            o1.x = acc[i][4] + bo1.x; o1.y = acc[i][5] + bo1.y;
            o1.z = acc[i][6] + bo1.z; o1.w = acc[i][7] + bo1.w;
            float* dst = out + (size_t)(b0 + tb * 16 + i) * V_ + v;
            *(float4*)dst = o0;
            *((float4*)dst + 1) = o1;
        }
    }
}

// ---------------------------------------------------------------------------
extern "C" void kernel_launch(void* const* d_in, const int* in_sizes, int n_in,
                              void* d_out_v, int out_size, void* d_ws, size_t ws_size,
                              hipStream_t stream)
{
    (void)in_sizes; (void)n_in; (void)out_size; (void)d_ws; (void)ws_size;
    const float* emb      = (const float*)d_in[0];
    const float* hidden   = (const float*)d_in[1];
    const float* inter    = (const float*)d_in[2];
    // d_in[3] delta_t_h: unused by reference
    const float* W_inter  = (const float*)d_in[4];
    const float* b_inter  = (const float*)d_in[5];
    const float* W_hidden = (const float*)d_in[6];
    const float* b_hidden = (const float*)d_in[7];
    const float* W_scale  = (const float*)d_in[8];
    // d_in[9] b_scale: cancels in softmax
    const float* W_lt1    = (const float*)d_in[10];
    const float* b_lt1    = (const float*)d_in[11];
    const float* W_ih     = (const float*)d_in[12];
    const float* W_hh     = (const float*)d_in[13];
    const float* b_ih     = (const float*)d_in[14];
    const float* b_hh     = (const float*)d_in[15];
    const float* W_out    = (const float*)d_in[16];
    const float* b_out    = (const float*)d_in[17];
    // d_in[18] input: unused by reference
    const int*   user_list = (const int*)d_in[19];

    float* out = (float*)d_out_v;
    float* ctx_stash = out + ST_CTX;
    float* WihT      = out + ST_WIHT;
    float* WhhT      = out + ST_WHHT;

    // weight transposes for coalesced GRU reads (stash in output region)
    transpose_kernel<<<dim3(512 / 32, 768 / 32), dim3(32, 8), 0, stream>>>(W_ih, WihT, 768, 512);
    transpose_kernel<<<dim3(256 / 32, 768 / 32), dim3(32, 8), 0, stream>>>(W_hh, WhhT, 768, 256);

    attn_kernel<<<B_, 256, 0, stream>>>(hidden, inter, W_inter, b_inter, W_hidden,
                                        b_hidden, W_scale, W_lt1, b_lt1, user_list,
                                        ctx_stash, out + OUT_ATTN_OFF);

    gru_kernel<<<B_ / 8, 256, 0, stream>>>(emb, hidden, ctx_stash, WihT, WhhT,
                                           b_ih, b_hh, out + OUT_HID_OFF,
                                           out + OUT_GRU_OFF, out + OUT_EMB_OFF);

    out_gemm<<<dim3((V_ + 255) / 256, B_ / 128), 256, 0, stream>>>(
        out + OUT_GRU_OFF, W_out, b_out, out);
}